// Round 5
// baseline (35.893 us; speedup 1.0000x reference)
//
#include <hip/hip_runtime.h>

// ResonantHTT embedding via two pair tables (b-major layout):
//   T[p01][b][u] = sum_a core0[i0,0,a,D0]*cos(phase[a]) * core1[i1,a,b,d1]
//       p01 = i0*16+i1, u = D0*8+d1   -> 256 x 16 x 64 f32 = 1 MB
//   F[p23][b][v] = sum_c core2[i2,b,c,d2] * core3[i3,c,0,d3]
//       p23 = i2*16+i3, v = d2*4+d3   -> 256 x 16 x 16 f32 = 256 KB
// Per token: out[n, u*16+v] = sum_b T[p01][b][u] * F[p23][b][v]
// k_out4: wave = 4 tokens, 16 lanes/token, lane owns an 8x8 (u,v) tile
// -> 1 KB operands per 64 outputs (4 B/output, 2x better than 4x4 tile).

typedef float f32x4 __attribute__((ext_vector_type(4)));

__global__ __launch_bounds__(256) void k_tables(
    const float* __restrict__ core0, const float* __restrict__ core1,
    const float* __restrict__ core2, const float* __restrict__ core3,
    const float* __restrict__ phase,
    float* __restrict__ T, float* __restrict__ F)
{
  const int gid = blockIdx.x * 256 + threadIdx.x;
  const int lane = threadIdx.x & 63;
  // each 16-lane segment holds cos(phase[0..15]); shuffle per a
  const float cown = cosf(phase[lane & 15]);
  if (blockIdx.x < 1024) {
    // ---- T: 262144 outputs, one per thread, coalesced b-major write ----
    const int p01 = gid >> 10, r = gid & 1023;
    const int b = r >> 6, u = r & 63;
    const int D0 = u >> 3, d1 = u & 7;
    const int i0 = p01 >> 4, i1 = p01 & 15;
    const float* c0 = core0 + i0 * 128 + D0;          // [a] stride 8
    const float* c1 = core1 + i1 * 2048 + b * 8 + d1; // [a] stride 128
    float acc = 0.f;
    #pragma unroll
    for (int a = 0; a < 16; ++a) {
      const float ca = __shfl(cown, a, 16);
      acc += c0[a * 8] * ca * c1[a * 128];
    }
    T[p01 * 1024 + b * 64 + u] = acc;
  } else {
    // ---- F: 65536 outputs, one per thread, coalesced b-major write ----
    const int o = gid - 262144;
    const int p23 = o >> 8, r = o & 255;
    const int b = r >> 4, v = r & 15;
    const int d2 = v >> 2, d3 = v & 3;
    const int i2 = p23 >> 4, i3 = p23 & 15;
    const float* c2 = core2 + i2 * 1024 + b * 64 + d2; // [c] stride 4
    const float* c3 = core3 + i3 * 64 + d3;            // [c] stride 4
    float acc = 0.f;
    #pragma unroll
    for (int c = 0; c < 16; ++c)
      acc += c2[c * 4] * c3[c * 4];
    F[p23 * 256 + b * 16 + v] = acc;
  }
}

__global__ __launch_bounds__(256) void k_out4(
    const int* __restrict__ ids, const float* __restrict__ T,
    const float* __restrict__ F, float* __restrict__ out)
{
  const int lane = threadIdx.x & 63;
  const int wv = threadIdx.x >> 6;
  // wave handles 4 consecutive tokens; 16 lanes per token
  const int tok = lane >> 4;                    // token within wave
  const int l16 = lane & 15;
  const int ug = l16 >> 1;                      // 8 u-groups of 8
  const int vg = l16 & 1;                       // 2 v-groups of 8
  const int n = (blockIdx.x * 4 + wv) * 4 + tok;

  const int id = ids[n];
  const int p01 = id >> 8, p23 = id & 255;

  const float* __restrict__ Tp = T + p01 * 1024 + ug * 8;  // + b*64
  const float* __restrict__ Fp = F + p23 * 256 + vg * 8;   // + b*16

  float acc[8][8];
  #pragma unroll
  for (int i = 0; i < 8; ++i)
    #pragma unroll
    for (int j = 0; j < 8; ++j) acc[i][j] = 0.f;

  #pragma unroll
  for (int b = 0; b < 16; ++b) {
    const f32x4 t0 = *reinterpret_cast<const f32x4*>(Tp + b * 64);
    const f32x4 t1 = *reinterpret_cast<const f32x4*>(Tp + b * 64 + 4);
    const f32x4 f0 = *reinterpret_cast<const f32x4*>(Fp + b * 16);
    const f32x4 f1 = *reinterpret_cast<const f32x4*>(Fp + b * 16 + 4);
    const float tv[8] = { t0.x, t0.y, t0.z, t0.w, t1.x, t1.y, t1.z, t1.w };
    const float fv[8] = { f0.x, f0.y, f0.z, f0.w, f1.x, f1.y, f1.z, f1.w };
    #pragma unroll
    for (int i = 0; i < 8; ++i)
      #pragma unroll
      for (int j = 0; j < 8; ++j)
        acc[i][j] += tv[i] * fv[j];
  }

  // out[n, (ug*8+i)*16 + vg*8 + j]; two f32x4 stores per row i.
  float* op = out + (size_t)n * 1024 + ug * 128 + vg * 8;
  #pragma unroll
  for (int i = 0; i < 8; ++i) {
    f32x4 lo = { acc[i][0], acc[i][1], acc[i][2], acc[i][3] };
    f32x4 hi = { acc[i][4], acc[i][5], acc[i][6], acc[i][7] };
    __builtin_nontemporal_store(lo, reinterpret_cast<f32x4*>(op + i * 16));
    __builtin_nontemporal_store(hi, reinterpret_cast<f32x4*>(op + i * 16 + 4));
  }
}

extern "C" void kernel_launch(void* const* d_in, const int* in_sizes, int n_in,
                              void* d_out, int out_size, void* d_ws, size_t ws_size,
                              hipStream_t stream) {
  const int*   ids   = (const int*)  d_in[0];
  const float* core0 = (const float*)d_in[1];
  const float* core1 = (const float*)d_in[2];
  const float* core2 = (const float*)d_in[3];
  const float* core3 = (const float*)d_in[4];
  const float* phase = (const float*)d_in[5];
  float* out = (float*)d_out;

  float* Tt = (float*)d_ws;                    // 1 MB
  float* Ft = (float*)d_ws + 256 * 1024;       // 256 KB

  const int tokens = in_sizes[0];              // 16384
  hipLaunchKernelGGL(k_tables, dim3(1280), dim3(256), 0, stream,
                     core0, core1, core2, core3, phase, Tt, Ft);
  hipLaunchKernelGGL(k_out4, dim3(tokens / 16), dim3(256), 0, stream,
                     ids, Tt, Ft, out);
}